// Round 9
// baseline (1136.425 us; speedup 1.0000x reference)
//
#include <hip/hip_runtime.h>
#include <math.h>

#define HIDDEN 4096
#define INTER  11008
#define NTOK   128

typedef _Float16 half8 __attribute__((ext_vector_type(8)));
typedef float    f32x4 __attribute__((ext_vector_type(4)));

__device__ __forceinline__ f32x4 mfma16(half8 a, half8 b, f32x4 c) {
  return __builtin_amdgcn_mfma_f32_16x16x32_f16(a, b, c, 0, 0, 0);
}

__device__ __forceinline__ _Float16 dq1(int v, float s, float m) {
  return (_Float16)((float)v * s + m);
}

// ---------------- Kernel 0: BW probe — stream first 45 MB of gate_up_q ------
// Diagnostic: per-dispatch hbm_gbps of this kernel == achievable coalesced
// int32-stream BW on this exact buffer. ~8-10 us. Remove once theory settles.
__global__ __launch_bounds__(256) void k_probe(const int* __restrict__ q,
                                               int* __restrict__ sink) {
  const size_t n = (size_t)INTER * HIDDEN * 2 / 8 / 4;  // int4 count (45 MB)
  int4 acc = {0, 0, 0, 0};
  for (size_t i = (size_t)blockIdx.x * 256 + threadIdx.x; i < n;
       i += (size_t)gridDim.x * 256) {
    const int4 v = ((const int4*)q)[i];
    acc.x += v.x; acc.y += v.y; acc.z += v.z; acc.w += v.w;
  }
  int s = acc.x + acc.y + acc.z + acc.w;
#pragma unroll
  for (int o = 32; o; o >>= 1) s += __shfl_xor(s, o);
  if ((threadIdx.x & 63) == 0) sink[blockIdx.x * 4 + (threadIdx.x >> 6)] = s;
}

// ---------------- Kernel 1: RMSNorm -> x fp16 ----------------
__global__ __launch_bounds__(256) void k_rmsnorm(const float* __restrict__ in,
                                                 const float* __restrict__ nw,
                                                 _Float16* __restrict__ xo) {
  const int tok = blockIdx.x;
  const int tid = threadIdx.x;
  const float* row = in + (size_t)tok * HIDDEN;
  float4 v[4];
  float ss = 0.f;
#pragma unroll
  for (int j = 0; j < 4; ++j) {
    v[j] = *(const float4*)&row[tid * 4 + j * 1024];
    ss += v[j].x * v[j].x + v[j].y * v[j].y + v[j].z * v[j].z + v[j].w * v[j].w;
  }
#pragma unroll
  for (int o = 32; o; o >>= 1) ss += __shfl_xor(ss, o);
  __shared__ float wsum[4];
  if ((tid & 63) == 0) wsum[tid >> 6] = ss;
  __syncthreads();
  ss = wsum[0] + wsum[1] + wsum[2] + wsum[3];
  const float rs = rsqrtf(ss * (1.f / HIDDEN) + 1e-6f);
#pragma unroll
  for (int j = 0; j < 4; ++j) {
    const int k = tid * 4 + j * 1024;
    const float4 w = *(const float4*)&nw[k];
    union { _Float16 h[4]; uint2 u; } p;
    p.h[0] = (_Float16)(v[j].x * rs * w.x);
    p.h[1] = (_Float16)(v[j].y * rs * w.y);
    p.h[2] = (_Float16)(v[j].z * rs * w.z);
    p.h[3] = (_Float16)(v[j].w * rs * w.w);
    *(uint2*)&xo[(size_t)tok * HIDDEN + k] = p.u;
  }
}

// ---------------- Kernel 2: gate/up GEMM, LDS-staged -> f32 partials --------
// Grid: 1376 = 344 coltiles x 4 ksplit (ks in low bits). Block: 4 waves.
// Tile: 32 inter rows x all 128 tokens; K-range 1024 per ks, 16 steps of 64.
// Per step: stage x[128][64] fp16 (16 KB, L2-hit) + q[32][64][2] raw int32
// (16 KB, HBM, COALESCED 512 B/row) into XOR-swizzled LDS (reg-staged,
// issue-early/write-late). Waves split M (tokens): wave w owns tokens
// 32w..32w+31. B fragments read raw ints from LDS, dequant in-reg.
__global__ __launch_bounds__(256) void k_gateup(const _Float16* __restrict__ x,
                                                const int* __restrict__ q,
                                                const float* __restrict__ sm,
                                                float* __restrict__ pg,
                                                float* __restrict__ pu) {
  const int tid  = threadIdx.x;
  const int lane = tid & 63;
  const int wave = tid >> 6;
  const int ks   = blockIdx.x & 3;
  const int ct   = blockIdx.x >> 2;
  const int rowbase = ct * 32;
  const int kbase   = ks * 1024;
  const int l15  = lane & 15;
  const int koff = (lane >> 4) * 8;

  __shared__ _Float16 xs[128 * 64];  // 16 KB, swizzled: byte ^= (tok&7)<<4
  __shared__ int      bs[32 * 128];  // 16 KB, swizzled: byte ^= (row&7)<<4
  char* xsb = (char*)xs;
  char* bsb = (char*)bs;

  f32x4 aG[2][2], aU[2][2];
  const f32x4 zz = {0.f, 0.f, 0.f, 0.f};
#pragma unroll
  for (int m = 0; m < 2; ++m)
#pragma unroll
    for (int n = 0; n < 2; ++n) { aG[m][n] = zz; aU[m][n] = zz; }

  // staging thread mapping (constant per thread)
  const int xtok = tid >> 3;   // 0..31 (+32 per j)
  const int xu   = tid & 7;    // 16B unit within 128B row-span
  const int brow = tid >> 5;   // 0..7  (+8 per j)
  const int bun  = tid & 31;   // 16B unit within 512B row-span

  const _Float16* xg = x + (size_t)xtok * HIDDEN + kbase + xu * 8;
  const int*      qg = q + (size_t)(rowbase + brow) * (HIDDEN * 2) + (size_t)kbase * 2 + bun * 4;

  int xoff[4], boff[4];
#pragma unroll
  for (int j = 0; j < 4; ++j) {
    const int tok = j * 32 + xtok;
    xoff[j] = (tok * 128 + xu * 16) ^ ((tok & 7) << 4);
    const int row = j * 8 + brow;
    boff[j] = (row * 512 + bun * 16) ^ ((row & 7) << 4);
  }

  int4 rx[4], rb[4];
#define GU_LOAD(S)                                                         \
  {                                                                        \
    _Pragma("unroll") for (int j = 0; j < 4; ++j)                          \
      rx[j] = *(const int4*)(xg + (size_t)j * 32 * HIDDEN + (S) * 64);     \
    _Pragma("unroll") for (int j = 0; j < 4; ++j)                          \
      rb[j] = *(const int4*)(qg + (size_t)j * 8 * (HIDDEN * 2) + (S) * 128); \
  }

  GU_LOAD(0);
  for (int s = 0; s < 16; ++s) {
#pragma unroll
    for (int j = 0; j < 4; ++j) *(int4*)(xsb + xoff[j]) = rx[j];
#pragma unroll
    for (int j = 0; j < 4; ++j) *(int4*)(bsb + boff[j]) = rb[j];
    __syncthreads();
    if (s < 15) GU_LOAD(s + 1);

#pragma unroll
    for (int kc = 0; kc < 2; ++kc) {
      const int grp = (kbase + s * 64 + kc * 32) >> 7;
      half8 a[2];
#pragma unroll
      for (int m = 0; m < 2; ++m) {
        const int tok = wave * 32 + m * 16 + l15;
        a[m] = *(const half8*)(xsb + ((tok * 128 + kc * 64 + koff * 2) ^ ((tok & 7) << 4)));
      }
#pragma unroll
      for (int n = 0; n < 2; ++n) {
        const int row  = n * 16 + l15;
        const int grow = rowbase + row;
        const float2 sg = *(const float2*)&sm[(size_t)grow * 128 + grp * 2];
        const float2 su = *(const float2*)&sm[(size_t)grow * 128 + 64 + grp * 2];
        const int base = row * 512 + kc * 256 + koff * 8;
        const int sw   = (row & 7) << 4;
        const int4 w0 = *(const int4*)(bsb + ((base +  0) ^ sw));
        const int4 w1 = *(const int4*)(bsb + ((base + 16) ^ sw));
        const int4 w2 = *(const int4*)(bsb + ((base + 32) ^ sw));
        const int4 w3 = *(const int4*)(bsb + ((base + 48) ^ sw));
        half8 bg, bu;
        bg[0] = dq1(w0.x, sg.x, sg.y); bu[0] = dq1(w0.y, su.x, su.y);
        bg[1] = dq1(w0.z, sg.x, sg.y); bu[1] = dq1(w0.w, su.x, su.y);
        bg[2] = dq1(w1.x, sg.x, sg.y); bu[2] = dq1(w1.y, su.x, su.y);
        bg[3] = dq1(w1.z, sg.x, sg.y); bu[3] = dq1(w1.w, su.x, su.y);
        bg[4] = dq1(w2.x, sg.x, sg.y); bu[4] = dq1(w2.y, su.x, su.y);
        bg[5] = dq1(w2.z, sg.x, sg.y); bu[5] = dq1(w2.w, su.x, su.y);
        bg[6] = dq1(w3.x, sg.x, sg.y); bu[6] = dq1(w3.y, su.x, su.y);
        bg[7] = dq1(w3.z, sg.x, sg.y); bu[7] = dq1(w3.w, su.x, su.y);
#pragma unroll
        for (int m = 0; m < 2; ++m) {
          aG[m][n] = mfma16(a[m], bg, aG[m][n]);
          aU[m][n] = mfma16(a[m], bu, aU[m][n]);
        }
      }
    }
    __syncthreads();
  }
#undef GU_LOAD

  // epilogue: waves own disjoint tokens -> direct stores, no reduction
  const int trow = (lane >> 4) * 4;
  float* pgb = pg + (size_t)ks * NTOK * INTER;
  float* pub = pu + (size_t)ks * NTOK * INTER;
#pragma unroll
  for (int m = 0; m < 2; ++m)
#pragma unroll
    for (int n = 0; n < 2; ++n) {
      const int col = rowbase + n * 16 + l15;
#pragma unroll
      for (int r = 0; r < 4; ++r) {
        const int token = wave * 32 + m * 16 + trow + r;
        pgb[(size_t)token * INTER + col] = aG[m][n][r];
        pub[(size_t)token * INTER + col] = aU[m][n][r];
      }
    }
}

// ---------------- Kernel 3: combine partials + SiLU -> h fp16 ----------------
__global__ __launch_bounds__(256) void k_silu(const float* __restrict__ pg,
                                              const float* __restrict__ pu,
                                              _Float16* __restrict__ h) {
  const size_t base = ((size_t)blockIdx.x * 256 + threadIdx.x) * 8;
  f32x4 g0 = {0,0,0,0}, g1 = {0,0,0,0}, u0 = {0,0,0,0}, u1 = {0,0,0,0};
#pragma unroll
  for (int ks = 0; ks < 4; ++ks) {
    const float* pgb = pg + (size_t)ks * NTOK * INTER + base;
    const float* pub = pu + (size_t)ks * NTOK * INTER + base;
    g0 += *(const f32x4*)pgb; g1 += *(const f32x4*)(pgb + 4);
    u0 += *(const f32x4*)pub; u1 += *(const f32x4*)(pub + 4);
  }
  union { _Float16 h[8]; uint4 u; } p;
#pragma unroll
  for (int j = 0; j < 4; ++j) {
    p.h[j]     = (_Float16)(g0[j] / (1.f + __expf(-g0[j])) * u0[j]);
    p.h[j + 4] = (_Float16)(g1[j] / (1.f + __expf(-g1[j])) * u1[j]);
  }
  *(uint4*)&h[base] = p.u;
}

// ---------------- Kernel 4: down GEMM, LDS-staged -> f32 partials ----------
// Grid: 1024 = 256 ntiles x 4 ksplit. Block: 4 waves. Tile: 16 hidden rows x
// 128 tokens; K-range 2752 per ks, 43 steps of 64. Same structure as gateup.
__global__ __launch_bounds__(256) void k_down(const _Float16* __restrict__ h,
                                              const int* __restrict__ q,
                                              const float* __restrict__ sm,
                                              float* __restrict__ pd) {
  const int tid  = threadIdx.x;
  const int lane = tid & 63;
  const int wave = tid >> 6;
  const int ks   = blockIdx.x & 3;
  const int nt   = blockIdx.x >> 2;
  const int rowbase = nt * 16;
  const int kbase   = ks * 2752;
  const int l15  = lane & 15;
  const int koff = (lane >> 4) * 8;

  __shared__ _Float16 hs[128 * 64];  // 16 KB
  __shared__ int      bs[16 * 64];   // 4 KB
  char* hsb = (char*)hs;
  char* bsb = (char*)bs;

  f32x4 acc[2];
  const f32x4 zz = {0.f, 0.f, 0.f, 0.f};
  acc[0] = zz; acc[1] = zz;

  const int htok = tid >> 3;   // 0..31 (+32 per j)
  const int hu   = tid & 7;
  const int brow = tid >> 4;   // 0..15
  const int bun  = tid & 15;   // 16B unit within 256B row-span

  const _Float16* hg = h + (size_t)htok * INTER + kbase + hu * 8;
  const int*      qg = q + (size_t)(rowbase + brow) * INTER + kbase + bun * 4;

  int hoff[4];
#pragma unroll
  for (int j = 0; j < 4; ++j) {
    const int tok = j * 32 + htok;
    hoff[j] = (tok * 128 + hu * 16) ^ ((tok & 7) << 4);
  }
  const int boff = (brow * 256 + bun * 16) ^ ((brow & 7) << 4);

  int4 rh[4], rb;
#define DN_LOAD(S)                                                        \
  {                                                                       \
    _Pragma("unroll") for (int j = 0; j < 4; ++j)                         \
      rh[j] = *(const int4*)(hg + (size_t)j * 32 * INTER + (S) * 64);     \
    rb = *(const int4*)(qg + (S) * 64);                                   \
  }

  DN_LOAD(0);
  for (int s = 0; s < 43; ++s) {
#pragma unroll
    for (int j = 0; j < 4; ++j) *(int4*)(hsb + hoff[j]) = rh[j];
    *(int4*)(bsb + boff) = rb;
    __syncthreads();
    if (s < 42) DN_LOAD(s + 1);

#pragma unroll
    for (int kc = 0; kc < 2; ++kc) {
      const int grp = (kbase + s * 64 + kc * 32) >> 7;
      half8 a[2];
#pragma unroll
      for (int m = 0; m < 2; ++m) {
        const int tok = wave * 32 + m * 16 + l15;
        a[m] = *(const half8*)(hsb + ((tok * 128 + kc * 64 + koff * 2) ^ ((tok & 7) << 4)));
      }
      const int row  = l15;
      const int grow = rowbase + row;
      const float2 sc = *(const float2*)&sm[(size_t)grow * 172 + grp * 2];
      const int base = row * 256 + kc * 128 + koff * 4;
      const int sw   = (row & 7) << 4;
      const int4 w0 = *(const int4*)(bsb + ((base +  0) ^ sw));
      const int4 w1 = *(const int4*)(bsb + ((base + 16) ^ sw));
      half8 bw;
      bw[0] = dq1(w0.x, sc.x, sc.y);
      bw[1] = dq1(w0.y, sc.x, sc.y);
      bw[2] = dq1(w0.z, sc.x, sc.y);
      bw[3] = dq1(w0.w, sc.x, sc.y);
      bw[4] = dq1(w1.x, sc.x, sc.y);
      bw[5] = dq1(w1.y, sc.x, sc.y);
      bw[6] = dq1(w1.z, sc.x, sc.y);
      bw[7] = dq1(w1.w, sc.x, sc.y);
#pragma unroll
      for (int m = 0; m < 2; ++m) acc[m] = mfma16(a[m], bw, acc[m]);
    }
    __syncthreads();
  }
#undef DN_LOAD

  const int trow = (lane >> 4) * 4;
  float* pb = pd + (size_t)ks * NTOK * HIDDEN;
  const int col = rowbase + l15;
#pragma unroll
  for (int m = 0; m < 2; ++m)
#pragma unroll
    for (int r = 0; r < 4; ++r) {
      const int token = wave * 32 + m * 16 + trow + r;
      pb[(size_t)token * HIDDEN + col] = acc[m][r];
    }
}

// ---------------- Kernel 5: sum 4 down partials + residual ----------------
__global__ __launch_bounds__(256) void k_final(const float* __restrict__ res,
                                               const float* __restrict__ pd,
                                               float* __restrict__ out) {
  const size_t base = ((size_t)blockIdx.x * 256 + threadIdx.x) * 8;
  f32x4 a0 = *(const f32x4*)&res[base];
  f32x4 a1 = *(const f32x4*)&res[base + 4];
#pragma unroll
  for (int ks = 0; ks < 4; ++ks) {
    const float* p = pd + (size_t)ks * NTOK * HIDDEN + base;
    a0 += *(const f32x4*)p;
    a1 += *(const f32x4*)(p + 4);
  }
  *(f32x4*)&out[base] = a0;
  *(f32x4*)&out[base + 4] = a1;
}

extern "C" void kernel_launch(void* const* d_in, const int* in_sizes, int n_in,
                              void* d_out, int out_size, void* d_ws, size_t ws_size,
                              hipStream_t stream) {
  const float* inp  = (const float*)d_in[0];
  const float* res  = (const float*)d_in[1];
  const float* nw   = (const float*)d_in[2];
  const int*   guq  = (const int*)d_in[3];
  const float* gusm = (const float*)d_in[4];
  const int*   dq   = (const int*)d_in[5];
  const float* dsm  = (const float*)d_in[6];
  float* out = (float*)d_out;

  char* ws = (char*)d_ws;
  _Float16* x    = (_Float16*)ws;                         // 1 MB
  _Float16* hbuf = (_Float16*)(ws + (1u << 20));          // 2.75 MB
  float*    pg   = (float*)(ws + (4u << 20));             // 22.5 MB
  float*    pu   = (float*)(ws + (28u << 20));            // 22.5 MB
  float*    pd   = (float*)(ws + (52u << 20));            // 8 MB
  int*      sink = (int*)(ws + (61u << 20));              // 16 KB probe sink

  k_probe<<<1024, 256, 0, stream>>>(guq, sink);
  k_rmsnorm<<<NTOK, 256, 0, stream>>>(inp, nw, x);
  k_gateup<<<(INTER / 32) * 4, 256, 0, stream>>>(x, guq, gusm, pg, pu);
  k_silu<<<(NTOK * INTER) / (256 * 8), 256, 0, stream>>>(pg, pu, hbuf);
  k_down<<<(HIDDEN / 16) * 4, 256, 0, stream>>>(hbuf, dq, dsm, pd);
  k_final<<<(NTOK * HIDDEN) / (256 * 8), 256, 0, stream>>>(res, pd, out);
}